// Round 15
// baseline (190.302 us; speedup 1.0000x reference)
//
#include <hip/hip_runtime.h>
#include <hip/hip_bf16.h>
#include <stdint.h>

// Problem constants
#define L_DIM 1024
#define C_DIM 512       // channels (elements)
#define CB4 256         // fp4 row stride in BYTES (512 elems * 4 bit)
#define N_BATCH 32
#define M_NEG 4096
#define NROWS (N_BATCH * L_DIM) // 32768

typedef float f32x4 __attribute__((ext_vector_type(4)));
typedef int i32x4 __attribute__((ext_vector_type(4)));
typedef int i32x8 __attribute__((ext_vector_type(8)));

// E stored as fp4 e2m1 scaled by 32 (clip at |x|=0.1875 ~ 4.3 sigma);
// e8m0 scale 122 (=2^-5) on both MFMA operands gives exact 1/1024 comp.
#define E4_SCALE 32.0f
#define MX_SCALE 122
#define FMT_FP4 4

// DMA immediate offset must be a compile-time constant -> template param.
template <int GOFF>
__device__ __forceinline__ void gl_lds16(const uint8_t* g, uint8_t* l) {
  __builtin_amdgcn_global_load_lds(
      (const __attribute__((address_space(1))) void*)g,
      (__attribute__((address_space(3))) void*)l, 16, GOFF, 0);
}

// fp4 e2m1 round-to-nearest encode of pre-scaled value.
__device__ __forceinline__ uint32_t fp4_enc(float x) {
  const uint32_t s = (__float_as_uint(x) >> 31) << 3;
  const float a = fabsf(x);
  uint32_t c;
  c = a < 0.25f ? 0u
    : a < 0.75f ? 1u
    : a < 1.25f ? 2u
    : a < 1.75f ? 3u
    : a < 2.5f  ? 4u
    : a < 3.5f  ? 5u
    : a < 5.0f  ? 6u : 7u;
  return s | c;
}

// fp4 operand tuple: HW reads only v[0:3] for FMT_FP4; upper half undef.
__device__ __forceinline__ i32x8 fp4_op(i32x4 d) {
  return __builtin_shufflevector(d, d, 0, 1, 2, 3, -1, -1, -1, -1);
}

// LDS swizzle phase (verified 0-conflict in R14): bank window = 128 B =
// two 64 B rows -> phase advances per 2 rows.
__device__ __forceinline__ int swz(int row) { return (row >> 1) & 3; }

// ---------------------------------------------------------------------------
// Kernel 1: row-wise L2 normalize fp32 [32768, 512] -> fp4 e2m1 (x32 scaled).
// Blocks 0..255 also zero the rowsum+simpos accumulators; block 0 zeroes
// the loss scalar.
// ---------------------------------------------------------------------------
__global__ __launch_bounds__(256) void k_normalize(const float* __restrict__ emb,
                                                   uint8_t* __restrict__ out,
                                                   float* __restrict__ zerobuf,
                                                   float* __restrict__ loss_out) {
  if (blockIdx.x < 256) zerobuf[blockIdx.x * 256 + threadIdx.x] = 0.0f;
  if (blockIdx.x == 0 && threadIdx.x == 0) loss_out[0] = 0.0f;
  const int lane = threadIdx.x & 63;
  const int wave = threadIdx.x >> 6;
  const long row = (long)blockIdx.x * 4 + wave;
  const float4* src = (const float4*)(emb + row * C_DIM);
  float4 v0 = src[2 * lane];
  float4 v1 = src[2 * lane + 1];
  float ss = v0.x * v0.x + v0.y * v0.y + v0.z * v0.z + v0.w * v0.w +
             v1.x * v1.x + v1.y * v1.y + v1.z * v1.z + v1.w * v1.w;
#pragma unroll
  for (int off = 1; off < 64; off <<= 1) ss += __shfl_xor(ss, off, 64);
  const float s = E4_SCALE / fmaxf(sqrtf(ss), 1e-12f);
  uint32_t pk = fp4_enc(v0.x * s)        | (fp4_enc(v0.y * s) << 4) |
                (fp4_enc(v0.z * s) << 8) | (fp4_enc(v0.w * s) << 12) |
                (fp4_enc(v1.x * s) << 16)| (fp4_enc(v1.y * s) << 20) |
                (fp4_enc(v1.z * s) << 24)| (fp4_enc(v1.w * s) << 28);
  ((uint32_t*)(out + row * CB4))[lane] = pk;
}

// ---------------------------------------------------------------------------
// Kernel 2 (FUSED), 3072 blocks:
// MODE 0 (bid < 1024): NEG-STATIONARY PERSISTENT TILES.
//   Block owns 128 neg rows: idx-gathered ONCE into 4 full-K LDS slabs
//   (sN[ks][128][64B] = 32 KB), then streams 8 E-tiles through an 8 KB
//   slab. Output rows = neg, cols = E -> rowsum reduce is REGISTER-ONLY
//   (in-thread sum over i,r + 2 q-shuffles + 1 atomic per E-col); the
//   LDS-transpose epilogue is gone and the neg slabs persist untouched.
//   Per block: 8x MFMA of R14, 1x prologue, B-gather traffic / 8.
//   XCD map: xcd=bid&7, slot=bid>>3: negTile=slot&31,
//   eGroup=xcd*4+(slot>>5) -> per XCD: all negs (1 MB) + E band (1 MB).
// MODE 1 (bid >= 1024): R14 structure verbatim (Gram x W epilogue).
// LDS 40960 B, 60ish VGPR + 64 AGPR -> 4 blocks/CU (38% occupancy, R13/14).
// ---------------------------------------------------------------------------
__global__ __launch_bounds__(256, 4) void k_gemm_fused(
    const uint8_t* __restrict__ E4, const int* __restrict__ idx,
    const float* __restrict__ W, float* __restrict__ rowsum,
    float* __restrict__ simpos) {
  __shared__ __align__(16) unsigned char smem_raw[40960];

  const int tid = threadIdx.x;
  const int lane = tid & 63;
  const int wave = tid >> 6;
  const int wm = wave >> 1, wn = wave & 1;
  const int q = lane >> 4, c16 = lane & 15;

  const int bid = blockIdx.x;

  if (bid < 1024) {
    // ================= MODE 0: neg-stationary =================
    uint8_t* sN = (uint8_t*)smem_raw;        // 4 slabs [128][64B] = 32 KB
    uint8_t* sE = sN + 32768;                // [128][64B] = 8 KB
    const int xcd = bid & 7, slot = bid >> 3;
    const long negBase = (long)(slot & 31) * 128;
    const long eBase0 = (long)(xcd * 4 + (slot >> 5)) * 1024;  // 8 tiles

    // Gather-stage the 128 neg rows, full K (8 DMAs/thread, once).
    const uint8_t* pN[2];
#pragma unroll
    for (int r = 0; r < 2; ++r) {
      const int c = r * 256 + tid;          // chunk 0..511 per slab
      const int rw = c >> 2, cb = c & 3;
      pN[r] = E4 + (long)idx[negBase + rw] * CB4 + (cb ^ swz(rw)) * 16;
    }
    gl_lds16<0>(pN[0], sN + tid * 16);
    gl_lds16<0>(pN[1], sN + (256 + tid) * 16);
    gl_lds16<64>(pN[0], sN + 8192 + tid * 16);
    gl_lds16<64>(pN[1], sN + 8192 + (256 + tid) * 16);
    gl_lds16<128>(pN[0], sN + 16384 + tid * 16);
    gl_lds16<128>(pN[1], sN + 16384 + (256 + tid) * 16);
    gl_lds16<192>(pN[0], sN + 24576 + tid * 16);
    gl_lds16<192>(pN[1], sN + 24576 + (256 + tid) * 16);

    // E staging pointers (advance 32768 B per tile).
    const uint8_t* pE[2];
#pragma unroll
    for (int r = 0; r < 2; ++r) {
      const int c = r * 256 + tid;
      const int rw = c >> 2, cb = c & 3;
      pE[r] = E4 + (eBase0 + rw) * CB4 + (cb ^ swz(rw)) * 16;
    }

    // Hoisted LDS fragment byte-offsets.
    int ldsN[4], ldsE[4];
#pragma unroll
    for (int j = 0; j < 4; ++j) {
      const int rowN = wm * 64 + j * 16 + c16;
      ldsN[j] = rowN * 64 + (q ^ swz(rowN)) * 16;
      const int rowE = wn * 64 + j * 16 + c16;
      ldsE[j] = rowE * 64 + (q ^ swz(rowE)) * 16;
    }

    for (int et = 0; et < 8; ++et) {
      f32x4 acc[4][4] = {};
      auto kstep = [&](int ks) {
        __syncthreads();
        i32x8 efr[4];
#pragma unroll
        for (int j = 0; j < 4; ++j)
          efr[j] = fp4_op(*(const i32x4*)(sE + ldsE[j]));
#pragma unroll
        for (int i = 0; i < 4; ++i) {
          i32x8 nf = fp4_op(*(const i32x4*)(sN + ks * 8192 + ldsN[i]));
#pragma unroll
          for (int j = 0; j < 4; ++j)
            acc[i][j] = __builtin_amdgcn_mfma_scale_f32_16x16x128_f8f6f4(
                nf, efr[j], acc[i][j], FMT_FP4, FMT_FP4,
                0, MX_SCALE, 0, MX_SCALE);
        }
        __syncthreads();
      };
      gl_lds16<0>(pE[0], sE + tid * 16);
      gl_lds16<0>(pE[1], sE + (256 + tid) * 16);
      kstep(0);
      gl_lds16<64>(pE[0], sE + tid * 16);
      gl_lds16<64>(pE[1], sE + (256 + tid) * 16);
      kstep(1);
      gl_lds16<128>(pE[0], sE + tid * 16);
      gl_lds16<128>(pE[1], sE + (256 + tid) * 16);
      kstep(2);
      gl_lds16<192>(pE[0], sE + tid * 16);
      gl_lds16<192>(pE[1], sE + (256 + tid) * 16);
      kstep(3);
      pE[0] += 32768;
      pE[1] += 32768;

      // Register-only epilogue: rowsum[E-col] += sum over 128 neg rows of
      // exp(sim). In-thread: sum over i,r; cross-lane: q-shuffles (16,32);
      // lanes q==0 atomically add (both wm waves hit the same cols).
      const long eCol = eBase0 + (long)et * 128 + wn * 64 + c16;
#pragma unroll
      for (int j = 0; j < 4; ++j) {
        float s = 0.0f;
#pragma unroll
        for (int i = 0; i < 4; ++i)
#pragma unroll
          for (int r = 0; r < 4; ++r) s += __expf(acc[i][j][r]);
        s += __shfl_xor(s, 16, 64);
        s += __shfl_xor(s, 32, 64);
        if (q == 0) atomicAdd(&rowsum[eCol + j * 16], s);
      }
    }
  } else {
    // ================= MODE 1: Gram x W (R14 verbatim) =================
    uint8_t* sA = (uint8_t*)smem_raw;        // [128][64B] = 8 KB
    uint8_t* sB = sA + 8192;                 // [128][64B] = 8 KB
    const int t = bid - 1024;
    const int xcd = t & 7, slot = t >> 3;
    const long n = xcd * 4 + (slot & 3);
    const int inner = slot >> 2;             // 0..63
    const long rowBase = (long)(inner & 7) * 128;
    const long colBase = (long)(inner >> 3) * 128;
    const long aBase = n * L_DIM + rowBase;

    const uint8_t* pA[2];
    const uint8_t* pB[2];
#pragma unroll
    for (int r = 0; r < 2; ++r) {
      const int c = r * 256 + tid;
      const int rw = c >> 2, cb = c & 3;
      pA[r] = E4 + (aBase + rw) * CB4 + (cb ^ swz(rw)) * 16;
      pB[r] = E4 + (n * L_DIM + colBase + rw) * CB4 + (cb ^ swz(rw)) * 16;
    }
    int ldsB[4], ldsA[4];
#pragma unroll
    for (int j = 0; j < 4; ++j) {
      const int rowB = wn * 64 + j * 16 + c16;
      ldsB[j] = rowB * 64 + (q ^ swz(rowB)) * 16;
      const int rowA = wm * 64 + j * 16 + c16;
      ldsA[j] = rowA * 64 + (q ^ swz(rowA)) * 16;
    }

    f32x4 acc[4][4] = {};
    auto kstep = [&]() {
      __syncthreads();
      i32x8 bfr[4];
#pragma unroll
      for (int j = 0; j < 4; ++j)
        bfr[j] = fp4_op(*(const i32x4*)(sB + ldsB[j]));
#pragma unroll
      for (int i = 0; i < 4; ++i) {
        i32x8 af = fp4_op(*(const i32x4*)(sA + ldsA[i]));
#pragma unroll
        for (int j = 0; j < 4; ++j)
          acc[i][j] = __builtin_amdgcn_mfma_scale_f32_16x16x128_f8f6f4(
              af, bfr[j], acc[i][j], FMT_FP4, FMT_FP4,
              0, MX_SCALE, 0, MX_SCALE);
      }
      __syncthreads();
    };
    gl_lds16<0>(pA[0], sA + tid * 16);
    gl_lds16<0>(pA[1], sA + (256 + tid) * 16);
    gl_lds16<0>(pB[0], sB + tid * 16);
    gl_lds16<0>(pB[1], sB + (256 + tid) * 16);
    kstep();
    gl_lds16<64>(pA[0], sA + tid * 16);
    gl_lds16<64>(pA[1], sA + (256 + tid) * 16);
    gl_lds16<64>(pB[0], sB + tid * 16);
    gl_lds16<64>(pB[1], sB + (256 + tid) * 16);
    kstep();
    gl_lds16<128>(pA[0], sA + tid * 16);
    gl_lds16<128>(pA[1], sA + (256 + tid) * 16);
    gl_lds16<128>(pB[0], sB + tid * 16);
    gl_lds16<128>(pB[1], sB + (256 + tid) * 16);
    kstep();
    gl_lds16<192>(pA[0], sA + tid * 16);
    gl_lds16<192>(pA[1], sA + (256 + tid) * 16);
    gl_lds16<192>(pB[0], sB + tid * 16);
    gl_lds16<192>(pB[1], sB + (256 + tid) * 16);
    kstep();

    float* G = (float*)smem_raw;  // [32 rows][pad 132] fp32 per pass
#pragma unroll
    for (int p = 0; p < 4; ++p) {
      if (wm == (p >> 1)) {
#pragma unroll
        for (int ii = 0; ii < 2; ++ii) {
          const int i = (p & 1) * 2 + ii;
#pragma unroll
          for (int j = 0; j < 4; ++j)
#pragma unroll
            for (int r = 0; r < 4; ++r)
              G[(ii * 16 + q * 4 + r) * 132 + wn * 64 + j * 16 + c16] =
                  acc[i][j][r];
        }
      }
      __syncthreads();
      {
        const int rr = tid >> 3;    // 0..31
        const int chunk = tid & 7;  // 16-float chunks
        const long krow = rowBase + p * 32 + rr;
        float v = 0.0f;
#pragma unroll
        for (int u = 0; u < 4; ++u) {
          const float4 g = *(const float4*)(G + rr * 132 + chunk * 16 + u * 4);
          const float4 w4 = *(const float4*)(W + krow * L_DIM + colBase +
                                             chunk * 16 + u * 4);
          v += g.x * w4.x + g.y * w4.y + g.z * w4.z + g.w * w4.w;
        }
        v += __shfl_xor(v, 1, 64);
        v += __shfl_xor(v, 2, 64);
        v += __shfl_xor(v, 4, 64);
        if (chunk == 0) atomicAdd(&simpos[n * L_DIM + krow], v);
      }
      __syncthreads();
    }
  }
}

// ---------------------------------------------------------------------------
// Kernel 3: 128-block finalize; out[0] pre-zeroed by k_normalize.
// loss = mean over rows of log(rowsum_neg + exp(simpos)) - simpos
// ---------------------------------------------------------------------------
__global__ __launch_bounds__(256) void k_finalize(const float* __restrict__ rowsum,
                                                  const float* __restrict__ simpos,
                                                  float* __restrict__ out) {
  const int gid = blockIdx.x * 256 + threadIdx.x;  // one row per thread
  const float sp = simpos[gid];
  float v = __logf(rowsum[gid] + __expf(sp)) - sp;
#pragma unroll
  for (int off = 1; off < 64; off <<= 1) v += __shfl_xor(v, off, 64);
  __shared__ float ws[4];
  if ((threadIdx.x & 63) == 0) ws[threadIdx.x >> 6] = v;
  __syncthreads();
  if (threadIdx.x == 0)
    atomicAdd(out, (ws[0] + ws[1] + ws[2] + ws[3]) * (1.0f / (float)NROWS));
}

// ---------------------------------------------------------------------------
// Workspace layout (bytes):
//   [0,       8388608)  E fp4 [32768, 256 B]   (x32 scaled e2m1)
//   [8388608, 8519680)  rowsum fp32 [32768]
//   [8519680, 8650752)  simpos fp32 [32768]    (contiguous with rowsum)
// ---------------------------------------------------------------------------
extern "C" void kernel_launch(void* const* d_in, const int* in_sizes, int n_in,
                              void* d_out, int out_size, void* d_ws, size_t ws_size,
                              hipStream_t stream) {
  const float* emb = (const float*)d_in[0];
  const float* weight = (const float*)d_in[1];
  const int* negidx = (const int*)d_in[2];
  float* out = (float*)d_out;
  char* ws = (char*)d_ws;

  uint8_t* E4 = (uint8_t*)ws;
  float* rowsum = (float*)(ws + 8388608);
  float* simpos = (float*)(ws + 8519680);

  k_normalize<<<NROWS / 4, 256, 0, stream>>>(emb, E4, rowsum, out);
  k_gemm_fused<<<3072, 256, 0, stream>>>(E4, negidx, weight, rowsum, simpos);
  k_finalize<<<NROWS / 256, 256, 0, stream>>>(rowsum, simpos, out);
}